// Round 6
// baseline (236.824 us; speedup 1.0000x reference)
//
#include <hip/hip_runtime.h>

// CrossModalAttentionScorer — round 6: 64x64-per-wave tiles (fix LDS-BW bound).
// B=16, R=1024, T=512, D=H=1024.
//
//   M2 = Wr @ Wq^T; Qp = NT(query, M2); cvec = q.(Wq br); bq cancels in softmax.
//   Fused: accS = NT(region,Qp)+cvec, accH = NT(Ws1+region*Ws2, query),
//   split-softmax stats per 64-col chunk; combine -> out.
//
// Round-5 lesson: wave=32x64 gives 25.6 FLOP per LDS byte -> fused kernel sits
// at ~71% of the ds_read_b128 ceiling (~52 TB/s), MfmaUtil capped at 31%.
// This round: wave=64x64 (85 FLOP/B, 3.3x less LDS read traffic). acc=128 AGPR
// so arch VGPR must stay <=128 for 2 waves/SIMD — enforced via
// __launch_bounds__(256, 2) (round 4 failed exactly here: 140+128 -> 1 w/SIMD).

#define BD 16
#define RD 1024
#define TD 512
#define DD 1024
#define BR (BD * RD)

typedef _Float16 half8 __attribute__((ext_vector_type(8)));
typedef _Float16 half4 __attribute__((ext_vector_type(4)));
typedef float floatx4 __attribute__((ext_vector_type(4)));

__device__ __forceinline__ float wave_sum(float v) {
#pragma unroll
  for (int off = 32; off > 0; off >>= 1) v += __shfl_down(v, off);
  return v;
}

// Pipelined 128x128x32 NT GEMM, 256 threads = 4 waves (2x2), wave = 64x64.
// FUSED: two B tiles (B0=Qp scores, B1=query H) + split-softmax stats.
// remap: 0 = natural, 1 = Qp (XCD m-strips), 2 = fused (XCD batch pairs).
template <bool FUSED>
__global__ __launch_bounds__(256, 2) void gemm_pipe(
    const _Float16* __restrict__ A, const _Float16* __restrict__ B0,
    const _Float16* __restrict__ B1, _Float16* __restrict__ C,
    float* __restrict__ Ms, float* __restrict__ Ls, float* __restrict__ Hs,
    const float* __restrict__ cvec, const _Float16* __restrict__ wsh,
    int N, int K, long sA, long sB, long sC, int remap) {
  constexpr int TT = FUSED ? 3 : 2;  // tiles per LDS buffer (A,B0[,B1])
  __shared__ __align__(16) _Float16 lds[2 * TT * 4096];
  __shared__ __align__(16) _Float16 wlds[FUSED ? 2048 : 16];

  const int lin = blockIdx.x + gridDim.x * (blockIdx.y + gridDim.y * blockIdx.z);
  int b, mt, nt;
  if (remap == 2) {          // 512 blocks: XCD s owns batches 2s,2s+1
    const int s = lin & 7, u = lin >> 3;
    b = 2 * s + (u >> 5);
    const int t = u & 31;
    mt = t >> 2; nt = t & 3;
  } else if (remap == 1) {   // 512 blocks: XCD s owns m-strip [8s,8s+8)
    const int s = lin & 7, u = lin >> 3;
    b = 0;
    mt = s * 8 + (u >> 3); nt = u & 7;
  } else {
    b = blockIdx.z; mt = blockIdx.y; nt = blockIdx.x;
  }
  const int m0 = mt * 128, n0 = nt * 128;
  A += (long)b * sA;
  B0 += (long)b * sB;
  if (FUSED) B1 += (long)b * sB;

  const int tid = threadIdx.x, lane = tid & 63, w = tid >> 6;
  const int wr = w >> 1, wc = w & 1;

  // Staging: 256 threads cover 64 rows x 4 chunks per pass; 2 passes per
  // 128-row tile. Chunk xor-swizzle (r3-proven: 0 bank conflicts); the swizzle
  // index (row>>1)&3 is invariant under row+=64.
  const int srow = tid >> 2;                  // 0..63
  const int slot = tid & 3;
  const int scol = (slot ^ ((srow >> 1) & 3)) * 8;
  const long offA = (long)(m0 + srow) * K + scol;   // +64*K for pass 2
  const long offB = (long)(n0 + srow) * K + scol;
  const long rstep = (long)64 * K;
  const int wofs = srow * 32 + slot * 8;      // halves; +2048 for pass 2

  if (FUSED) *(int4*)&wlds[tid * 8] = *(const int4*)&wsh[tid * 8];  // Ws1|Ws2

  const int NK = K / 32;
  int4 pA0, pA1, pP0, pP1, pQ0, pQ1;
  pA0 = *(const int4*)(A + offA);
  pA1 = *(const int4*)(A + offA + rstep);
  pP0 = *(const int4*)(B0 + offB);
  pP1 = *(const int4*)(B0 + offB + rstep);
  if (FUSED) {
    pQ0 = *(const int4*)(B1 + offB);
    pQ1 = *(const int4*)(B1 + offB + rstep);
  }
  *(int4*)&lds[wofs] = pA0;
  *(int4*)&lds[wofs + 2048] = pA1;
  *(int4*)&lds[4096 + wofs] = pP0;
  *(int4*)&lds[4096 + wofs + 2048] = pP1;
  if (FUSED) {
    *(int4*)&lds[8192 + wofs] = pQ0;
    *(int4*)&lds[8192 + wofs + 2048] = pQ1;
  }
  if (NK > 1) {
    pA0 = *(const int4*)(A + offA + 32);
    pA1 = *(const int4*)(A + offA + rstep + 32);
    pP0 = *(const int4*)(B0 + offB + 32);
    pP1 = *(const int4*)(B0 + offB + rstep + 32);
    if (FUSED) {
      pQ0 = *(const int4*)(B1 + offB + 32);
      pQ1 = *(const int4*)(B1 + offB + rstep + 32);
    }
  }
  __syncthreads();

  floatx4 accS[4][4] = {};
  floatx4 accH[4][4] = {};  // dead when !FUSED
  const int fr = lane & 15, g = lane >> 4;
  const int fs = (g ^ ((fr >> 1) & 3)) * 8;

  for (int kt = 0; kt < NK; ++kt) {
    const int cur = (kt & 1) * TT * 4096;
    const int nxt = ((kt + 1) & 1) * TT * 4096;
    if (kt + 1 < NK) {  // stage tile kt+1: regs -> LDS buf nxt
      *(int4*)&lds[nxt + wofs] = pA0;
      *(int4*)&lds[nxt + wofs + 2048] = pA1;
      *(int4*)&lds[nxt + 4096 + wofs] = pP0;
      *(int4*)&lds[nxt + 4096 + wofs + 2048] = pP1;
      if (FUSED) {
        *(int4*)&lds[nxt + 8192 + wofs] = pQ0;
        *(int4*)&lds[nxt + 8192 + wofs + 2048] = pQ1;
      }
    }
    if (kt + 2 < NK) {  // prefetch tile kt+2 -> regs (full iter in flight)
      const long go = (long)(kt + 2) * 32;
      pA0 = *(const int4*)(A + offA + go);
      pA1 = *(const int4*)(A + offA + rstep + go);
      pP0 = *(const int4*)(B0 + offB + go);
      pP1 = *(const int4*)(B0 + offB + rstep + go);
      if (FUSED) {
        pQ0 = *(const int4*)(B1 + offB + go);
        pQ1 = *(const int4*)(B1 + offB + rstep + go);
      }
    }
    half8 af[4], bp[4], bq[4], w1f, w2f;
#pragma unroll
    for (int i = 0; i < 4; ++i)
      af[i] = *(const half8*)&lds[cur + (64 * wr + 16 * i + fr) * 32 + fs];
#pragma unroll
    for (int j = 0; j < 4; ++j)
      bp[j] = *(const half8*)&lds[cur + 4096 + (64 * wc + 16 * j + fr) * 32 + fs];
    if (FUSED) {
#pragma unroll
      for (int j = 0; j < 4; ++j)
        bq[j] = *(const half8*)&lds[cur + 8192 + (64 * wc + 16 * j + fr) * 32 + fs];
      w1f = *(const half8*)&wlds[kt * 32 + g * 8];
      w2f = *(const half8*)&wlds[1024 + kt * 32 + g * 8];
    }
#pragma unroll
    for (int i = 0; i < 4; ++i)
#pragma unroll
      for (int j = 0; j < 4; ++j)
        accS[i][j] = __builtin_amdgcn_mfma_f32_16x16x32_f16(af[i], bp[j], accS[i][j], 0, 0, 0);
    if (FUSED) {
#pragma unroll
      for (int i = 0; i < 4; ++i) af[i] = w1f + af[i] * w2f;  // A' for H
#pragma unroll
      for (int i = 0; i < 4; ++i)
#pragma unroll
        for (int j = 0; j < 4; ++j)
          accH[i][j] = __builtin_amdgcn_mfma_f32_16x16x32_f16(af[i], bq[j], accH[i][j], 0, 0, 0);
    }
    __syncthreads();
  }

  // C/D layout: col = lane&15 (=fr), row = g*4 + reg.
  const int cr = g * 4, cc = fr;
  if (!FUSED) {
    _Float16* Cw = C + (long)b * sC;
#pragma unroll
    for (int i = 0; i < 4; ++i)
#pragma unroll
      for (int r = 0; r < 4; ++r)
#pragma unroll
        for (int j = 0; j < 4; ++j)
          Cw[(long)(m0 + 64 * wr + 16 * i + cr + r) * N + n0 + 64 * wc + 16 * j + cc] =
              (_Float16)accS[i][j][r];
  } else {
    float cv[4];
#pragma unroll
    for (int j = 0; j < 4; ++j)
      cv[j] = cvec[(long)b * TD + n0 + 64 * wc + 16 * j + cc];
    const int chunk = nt * 2 + wc;  // 64-col chunk 0..7
    const long rowBase = (long)b * RD + m0 + 64 * wr + cr;
#pragma unroll
    for (int i = 0; i < 4; ++i) {
#pragma unroll
      for (int r = 0; r < 4; ++r) {
        float mx = -1e30f;
#pragma unroll
        for (int j = 0; j < 4; ++j) mx = fmaxf(mx, accS[i][j][r] + cv[j]);
        mx = fmaxf(mx, __shfl_xor(mx, 1));
        mx = fmaxf(mx, __shfl_xor(mx, 2));
        mx = fmaxf(mx, __shfl_xor(mx, 4));
        mx = fmaxf(mx, __shfl_xor(mx, 8));
        float l = 0.f, hs = 0.f;
#pragma unroll
        for (int j = 0; j < 4; ++j) {
          const float e = __expf(accS[i][j][r] + cv[j] - mx);
          l += e;
          hs += e * accH[i][j][r];
        }
        l += __shfl_xor(l, 1); hs += __shfl_xor(hs, 1);
        l += __shfl_xor(l, 2); hs += __shfl_xor(hs, 2);
        l += __shfl_xor(l, 4); hs += __shfl_xor(hs, 4);
        l += __shfl_xor(l, 8); hs += __shfl_xor(hs, 8);
        if (cc == 0) {
          const long idx = (long)chunk * BR + rowBase + 16 * i + r;
          Ms[idx] = mx;
          Ls[idx] = l;
          Hs[idx] = hs;
        }
      }
    }
  }
}

// Combine 8 chunk-stats per row: out = HS/L + rdvec + bs.
__global__ __launch_bounds__(256) void combine(
    const float* __restrict__ Ms, const float* __restrict__ Ls,
    const float* __restrict__ Hs, const float* __restrict__ rdvec,
    const float* __restrict__ bs, float* __restrict__ out) {
  const int row = blockIdx.x * 256 + threadIdx.x;
  float mv[8];
  float gm = -1e30f;
#pragma unroll
  for (int c = 0; c < 8; ++c) {
    mv[c] = Ms[(long)c * BR + row];
    gm = fmaxf(gm, mv[c]);
  }
  float L = 0.f, HS = 0.f;
#pragma unroll
  for (int c = 0; c < 8; ++c) {
    const float s = __expf(mv[c] - gm);
    L += Ls[(long)c * BR + row] * s;
    HS += Hs[(long)c * BR + row] * s;
  }
  out[row] = HS / L + rdvec[row] + bs[0];
}

// prep: blocks [0,1024) Wr->fp16, [1024,2048) Wq->fp16, [2048,2050) Ws1|Ws2,
// [2050,2306) wqbr = Wq @ br.
__global__ __launch_bounds__(256) void prep(
    const float* __restrict__ Wr, const float* __restrict__ Wq,
    const float* __restrict__ Ws, const float* __restrict__ br,
    _Float16* __restrict__ Wr16, _Float16* __restrict__ Wq16,
    _Float16* __restrict__ Ws16, float* __restrict__ wqbr) {
  const int blk = blockIdx.x, tid = threadIdx.x;
  if (blk < 2050) {
    const float* src;
    _Float16* dst;
    long i;
    if (blk < 1024) { src = Wr; dst = Wr16; i = (long)blk * 1024 + tid * 4; }
    else if (blk < 2048) { src = Wq; dst = Wq16; i = (long)(blk - 1024) * 1024 + tid * 4; }
    else { src = Ws + DD; dst = Ws16; i = (long)(blk - 2048) * 1024 + tid * 4; }
    const float4 v = *(const float4*)&src[i];
    half4 h = {(_Float16)v.x, (_Float16)v.y, (_Float16)v.z, (_Float16)v.w};
    *(half4*)&dst[i] = h;
  } else {
    const int row = (blk - 2050) * 4 + (tid >> 6);
    const int lane = tid & 63;
    const float* x = Wq + (long)row * DD;
    float s = 0.f;
    for (int k = lane; k < DD; k += 64) s += x[k] * br[k];
    s = wave_sum(s);
    if (lane == 0) wqbr[row] = s;
  }
}

// One block per (b,r) row: region -> fp16, rdvec[row] = region.Ws0.
__global__ __launch_bounds__(256) void conv_region(
    const float* __restrict__ region, const float* __restrict__ Ws,
    _Float16* __restrict__ r16, float* __restrict__ rdvec) {
  const long row = blockIdx.x;
  const int tid = threadIdx.x, lane = tid & 63, wid = tid >> 6;
  const long i = row * DD + tid * 4;
  const float4 v = *(const float4*)&region[i];
  half4 h = {(_Float16)v.x, (_Float16)v.y, (_Float16)v.z, (_Float16)v.w};
  *(half4*)&r16[i] = h;
  const float4 w0 = *(const float4*)&Ws[tid * 4];
  float rd = v.x * w0.x + v.y * w0.y + v.z * w0.z + v.w * w0.w;
  rd = wave_sum(rd);
  __shared__ float sm[4];
  if (lane == 0) sm[wid] = rd;
  __syncthreads();
  if (tid == 0) rdvec[row] = sm[0] + sm[1] + sm[2] + sm[3];
}

// One block per (b,t) row: query -> fp16, cvec[row] = q.(Wq br).
__global__ __launch_bounds__(256) void conv_query(
    const float* __restrict__ query, const float* __restrict__ wqbr,
    _Float16* __restrict__ q16, float* __restrict__ cvec) {
  const long row = blockIdx.x;
  const int tid = threadIdx.x, lane = tid & 63, wid = tid >> 6;
  const long i = row * DD + tid * 4;
  const float4 v = *(const float4*)&query[i];
  half4 h = {(_Float16)v.x, (_Float16)v.y, (_Float16)v.z, (_Float16)v.w};
  *(half4*)&q16[i] = h;
  const float4 w = *(const float4*)&wqbr[tid * 4];
  float c = v.x * w.x + v.y * w.y + v.z * w.z + v.w * w.w;
  c = wave_sum(c);
  __shared__ float sm[4];
  if (lane == 0) sm[wid] = c;
  __syncthreads();
  if (tid == 0) cvec[row] = sm[0] + sm[1] + sm[2] + sm[3];
}

extern "C" void kernel_launch(void* const* d_in, const int* in_sizes, int n_in,
                              void* d_out, int out_size, void* d_ws, size_t ws_size,
                              hipStream_t stream) {
  const float* region = (const float*)d_in[0];
  const float* query  = (const float*)d_in[1];
  const float* Wr     = (const float*)d_in[2];
  const float* br     = (const float*)d_in[3];
  const float* Wq     = (const float*)d_in[4];
  // d_in[5] = bq: t-constant per score row, cancels in softmax.
  const float* Ws     = (const float*)d_in[6];
  const float* bs     = (const float*)d_in[7];
  float* out = (float*)d_out;

  // ws layout (~74 MiB).
  char* p = (char*)d_ws;
  _Float16* region16 = (_Float16*)p;                   // 32 MiB
  _Float16* query16  = (_Float16*)(p + (32u << 20));   // 16 MiB
  _Float16* Qp       = (_Float16*)(p + (48u << 20));   // 16 MiB
  _Float16* Wr16     = (_Float16*)(p + (64u << 20));   // 2 MiB
  _Float16* Wq16     = (_Float16*)(p + (66u << 20));   // 2 MiB
  _Float16* M2       = (_Float16*)(p + (68u << 20));   // 2 MiB
  _Float16* Ws16     = (_Float16*)(p + (70u << 20));   // 4 KiB (Ws1|Ws2)
  float*    wqbr     = (float*)(p + (70u << 20) + 65536);
  float*    cvec     = wqbr + 1024;
  float*    rdvec    = cvec + BD * TD;
  float*    Ms       = (float*)(p + (72u << 20));      // 3 x 512 KiB stats
  float*    Ls       = Ms + 8 * BR;
  float*    Hs       = Ls + 8 * BR;

  prep<<<dim3(2306), 256, 0, stream>>>(Wr, Wq, Ws, br, Wr16, Wq16, Ws16, wqbr);
  conv_region<<<dim3(BD * RD), 256, 0, stream>>>(region, Ws, region16, rdvec);
  conv_query<<<dim3(BD * TD), 256, 0, stream>>>(query, wqbr, query16, cvec);

  // M2 = Wr @ Wq^T  [D,D] fp16.
  gemm_pipe<false><<<dim3(8, 8, 1), 256, 0, stream>>>(
      Wr16, Wq16, nullptr, M2, nullptr, nullptr, nullptr, nullptr, nullptr,
      DD, DD, 0, 0, 0, 0);
  // Qp = query @ M2^T  [B*T, D] fp16, XCD m-strips.
  gemm_pipe<false><<<dim3(8, 64, 1), 256, 0, stream>>>(
      query16, M2, nullptr, Qp, nullptr, nullptr, nullptr, nullptr, nullptr,
      DD, DD, 0, 0, 0, 1);
  // Fused S/H + split-softmax stats, XCD batch-pairs.
  gemm_pipe<true><<<dim3(TD / 128, RD / 128, BD), 256, 0, stream>>>(
      region16, Qp, query16, nullptr, Ms, Ls, Hs, cvec, Ws16,
      TD, DD, (long)RD * DD, (long)TD * DD, 0, 2);
  // out = HS/L + region.Ws0 + bs.
  combine<<<dim3(BR / 256), 256, 0, stream>>>(Ms, Ls, Hs, rdvec, bs, out);
}